// Round 8
// baseline (1575.452 us; speedup 1.0000x reference)
//
#include <hip/hip_runtime.h>

#define HID 51
#define TLEN 1024
#define NBATCH 4
#define NW 16             // waves per block
#define NTH (NW * 64)

typedef __attribute__((ext_vector_type(8))) short bf16x8;
typedef __attribute__((ext_vector_type(4))) float f32x4;

#define LOG2E 1.4426950408889634f

__device__ __forceinline__ float frcp(float v){ return __builtin_amdgcn_rcpf(v); }
// input already scaled by log2e (or 2*log2e for tanh-gate)
__device__ __forceinline__ float sigm2(float v){ return frcp(1.f + __builtin_amdgcn_exp2f(-v)); }
__device__ __forceinline__ float tanh_c(float c){   // c in true domain
    return fmaf(2.f, frcp(1.f + __builtin_amdgcn_exp2f(-2.f*LOG2E*c)), -1.f);
}
__device__ __forceinline__ unsigned short f2bf(float f){
    unsigned u = __float_as_uint(f);
    return (unsigned short)((u + 0x7FFFu + ((u>>16)&1u)) >> 16);   // RNE f32->bf16
}
__device__ __forceinline__ float bf2f(unsigned short b){ return __uint_as_float(((unsigned)b)<<16); }

// LDS h layout = MFMA B-fragment-linear (validated R4): lane l reads 16B at
// short-index kb*512 + l*8 covering k = 32*kb + 8*(l>>4) + 0..7, n = l&15.
// Writer (unit j, col n): short-index = (j>>5)*512 + (n + ((j>>3)&3)*16)*8 + (j&7).

__global__ __launch_bounds__(NTH, 4)
void lstm2_mfma(const float* __restrict__ x,
                const float* __restrict__ W_ih0, const float* __restrict__ W_hh0,
                const float* __restrict__ b_ih0, const float* __restrict__ b_hh0,
                const float* __restrict__ W_ih1, const float* __restrict__ W_hh1,
                const float* __restrict__ b_ih1, const float* __restrict__ b_hh1,
                const float* __restrict__ W_lin, const float* __restrict__ b_lin,
                float* __restrict__ out)
{
    const int tid = threadIdx.x;
    const int w = tid >> 6;          // wave 0..15; waves 0..12 compute tile m=w
    const int l = tid & 63;          // lane
    const int n = l & 15;            // batch col / A-row slot
    const int p = l >> 4;            // lane group 0..3
    const int m = w;                 // M-tile id
    const bool cw = (m < 13);        // compute wave?

    __shared__ short H0hi[2][1024], H0lo[2][1024];
    __shared__ short H1hi[2][1024], H1lo[2][1024];
    __shared__ __align__(16) float PS[2][16][16];

    for (int i = tid; i < 1024; i += NTH){
        H0hi[0][i]=0; H0hi[1][i]=0; H0lo[0][i]=0; H0lo[1][i]=0;
        H1hi[0][i]=0; H1hi[1][i]=0; H1lo[0][i]=0; H1lo[1][i]=0;
    }
    if (tid < 2*16*16) (&PS[0][0][0])[tid] = 0.f;

    // ---- persistent weight fragments & epilogue constants (one tile) ----
    bf16x8 Ahi0[2], Alo0[2], Ahi1[4], Alo1[4];
    f32x4 bias0v, bias1v, wih0v;
    float wlinv = 0.f;
    int   widx4 = 0;

    {
        const int ar = 16*m + n;              // A-row = gate g = 4j + r
        const int aj = ar >> 2, arr = ar & 3;
        const bool rowv = cw && (aj < HID);
        const int orow = arr*HID + aj;
        const float gsc = (arr == 2) ? 2.f*LOG2E : LOG2E;   // pre-scale into exp2 domain
        #pragma unroll
        for (int kb=0; kb<2; ++kb){
            bf16x8 hi, lo;
            #pragma unroll
            for (int jj=0; jj<8; ++jj){
                const int k = kb*32 + 8*p + jj;
                const float wv = (rowv && k < HID) ? gsc * W_hh0[orow*HID + k] : 0.f;
                const unsigned short hb = f2bf(wv);
                hi[jj] = (short)hb;
                lo[jj] = (short)f2bf(wv - bf2f(hb));
            }
            Ahi0[kb] = hi; Alo0[kb] = lo;
        }
        #pragma unroll
        for (int kb=0; kb<4; ++kb){
            bf16x8 hi, lo;
            #pragma unroll
            for (int jj=0; jj<8; ++jj){
                const int k = kb*32 + 8*p + jj;   // 0..127: [h0 (64) ; h1 (64)]
                float wv = 0.f;
                if (rowv){
                    if (k < 64) { if (k < HID) wv = W_ih1[orow*HID + k]; }
                    else        { const int kk = k - 64; if (kk < HID) wv = W_hh1[orow*HID + kk]; }
                }
                wv *= gsc;
                const unsigned short hb = f2bf(wv);
                hi[jj] = (short)hb;
                lo[jj] = (short)f2bf(wv - bf2f(hb));
            }
            Ahi1[kb] = hi; Alo1[kb] = lo;
        }
        const int je = 4*m + p;               // unit this lane owns in epilogue
        const bool jev = cw && (je < HID);
        #pragma unroll
        for (int r4=0; r4<4; ++r4){
            const float gs4 = (r4 == 2) ? 2.f*LOG2E : LOG2E;
            const int oe = r4*HID + je;
            bias0v[r4] = jev ? gs4 * (b_ih0[oe] + b_hh0[oe]) : 0.f;
            bias1v[r4] = jev ? gs4 * (b_ih1[oe] + b_hh1[oe]) : 0.f;
            wih0v[r4] = jev ? gs4 * W_ih0[oe] : 0.f;
        }
        wlinv = jev ? W_lin[je] : 0.f;
        widx4 = ((je>>5)<<9) + (n + ((je>>3)&3)*16)*8 + (je&7);
    }

    const long long bb = (long long)blockIdx.x * NBATCH;
    const float* xr = x + (bb + (n < NBATCH ? n : NBATCH-1)) * TLEN;
    float xv = xr[0];
    float c0a = 0.f, c1a = 0.f;
    const float blin = b_lin[0];

    __syncthreads();

    // Pipelined loop: iter s = layer0(s) || layer1(s-1) || out(s-2). ONE barrier.
    for (int s = 0; s <= TLEN; ++s){
        const int pw = s & 1, pr = pw ^ 1;
        const float xnx = xr[(s+1 < TLEN) ? s+1 : TLEN-1];

        // fragment reads: h0(s-1) (both layers) and h1(s-2) — compute waves only
        bf16x8 r0h[2], r0l[2], r1h[2], r1l[2];
        if (cw){
            #pragma unroll
            for (int kb=0; kb<2; ++kb){
                r0h[kb] = *reinterpret_cast<const bf16x8*>(&H0hi[pr][kb*512 + l*8]);
                r0l[kb] = *reinterpret_cast<const bf16x8*>(&H0lo[pr][kb*512 + l*8]);
                r1h[kb] = *reinterpret_cast<const bf16x8*>(&H1hi[pw][kb*512 + l*8]);
                r1l[kb] = *reinterpret_cast<const bf16x8*>(&H1lo[pw][kb*512 + l*8]);
            }
        }

        // out(s-2): wave 13 sums PS written at iter s-1 (cols w=13..15 stay 0)
        if (s >= 2 && w == 13 && l < NBATCH){
            const float4 p0 = *reinterpret_cast<const float4*>(&PS[pr][l][0]);
            const float4 p1 = *reinterpret_cast<const float4*>(&PS[pr][l][4]);
            const float4 p2 = *reinterpret_cast<const float4*>(&PS[pr][l][8]);
            const float4 p3 = *reinterpret_cast<const float4*>(&PS[pr][l][12]);
            const float s01 = (p0.x + p0.y) + (p0.z + p0.w);
            const float s23 = (p1.x + p1.y) + (p1.z + p1.w);
            const float s45 = (p2.x + p2.y) + (p2.z + p2.w);
            const float s67 = (p3.x + p3.y) + (p3.z + p3.w);
            out[(bb + l)*TLEN + (s-2)] = ((s01 + s23) + (s45 + s67)) + blin;
        }

        // ---------------- layer 0, step s ----------------
        if (cw && s < TLEN){
            f32x4 a0 = bias0v;
            #pragma unroll
            for (int r4=0; r4<4; ++r4) a0[r4] = fmaf(xv, wih0v[r4], a0[r4]);
            f32x4 a1 = {0.f,0.f,0.f,0.f}, a2 = {0.f,0.f,0.f,0.f};
            #pragma unroll
            for (int kb=0; kb<2; ++kb){
                a0 = __builtin_amdgcn_mfma_f32_16x16x32_bf16(Ahi0[kb], r0h[kb], a0, 0,0,0);
                a1 = __builtin_amdgcn_mfma_f32_16x16x32_bf16(Ahi0[kb], r0l[kb], a1, 0,0,0);
                a2 = __builtin_amdgcn_mfma_f32_16x16x32_bf16(Alo0[kb], r0h[kb], a2, 0,0,0);
            }
            const f32x4 pre = (a0 + a1) + a2;
            const float gi = sigm2(pre[0]);
            const float gf = sigm2(pre[1]);
            const float gg = fmaf(2.f, sigm2(pre[2]), -1.f);   // tanh via 2*log2e prescale
            const float go = sigm2(pre[3]);
            c0a = fmaf(gf, c0a, gi*gg);
            const float hv = go * tanh_c(c0a);
            const unsigned short hh = f2bf(hv);
            H0hi[pw][widx4] = (short)hh;
            H0lo[pw][widx4] = (short)f2bf(hv - bf2f(hh));
        }

        // ---------------- layer 1, step s-1 + projection ----------------
        if (cw && s >= 1){
            f32x4 b0 = bias1v;
            f32x4 b1 = {0.f,0.f,0.f,0.f}, b2 = {0.f,0.f,0.f,0.f};
            #pragma unroll
            for (int kb=0; kb<2; ++kb){
                b0 = __builtin_amdgcn_mfma_f32_16x16x32_bf16(Ahi1[kb],   r0h[kb], b0, 0,0,0);
                b1 = __builtin_amdgcn_mfma_f32_16x16x32_bf16(Ahi1[kb],   r0l[kb], b1, 0,0,0);
                b2 = __builtin_amdgcn_mfma_f32_16x16x32_bf16(Alo1[kb],   r0h[kb], b2, 0,0,0);
                b0 = __builtin_amdgcn_mfma_f32_16x16x32_bf16(Ahi1[kb+2], r1h[kb], b0, 0,0,0);
                b1 = __builtin_amdgcn_mfma_f32_16x16x32_bf16(Ahi1[kb+2], r1l[kb], b1, 0,0,0);
                b2 = __builtin_amdgcn_mfma_f32_16x16x32_bf16(Alo1[kb+2], r1h[kb], b2, 0,0,0);
            }
            const f32x4 pre = (b0 + b1) + b2;
            const float gi = sigm2(pre[0]);
            const float gf = sigm2(pre[1]);
            const float gg = fmaf(2.f, sigm2(pre[2]), -1.f);
            const float go = sigm2(pre[3]);
            c1a = fmaf(gf, c1a, gi*gg);
            const float hv = go * tanh_c(c1a);
            const unsigned short hh = f2bf(hv);
            H1hi[pr][widx4] = (short)hh;
            H1lo[pr][widx4] = (short)f2bf(hv - bf2f(hh));
            float ph = hv * wlinv;
            ph += __shfl_xor(ph, 16, 64);
            ph += __shfl_xor(ph, 32, 64);
            if (l < 16) PS[pw][l][w] = ph;
        }

        __syncthreads();
        xv = xnx;
    }

    // tail: out(1023) from PS written at s=1024 (parity 0)
    if (w == 13 && l < NBATCH){
        const float4 p0 = *reinterpret_cast<const float4*>(&PS[0][l][0]);
        const float4 p1 = *reinterpret_cast<const float4*>(&PS[0][l][4]);
        const float4 p2 = *reinterpret_cast<const float4*>(&PS[0][l][8]);
        const float4 p3 = *reinterpret_cast<const float4*>(&PS[0][l][12]);
        const float s01 = (p0.x + p0.y) + (p0.z + p0.w);
        const float s23 = (p1.x + p1.y) + (p1.z + p1.w);
        const float s45 = (p2.x + p2.y) + (p2.z + p2.w);
        const float s67 = (p3.x + p3.y) + (p3.z + p3.w);
        out[(bb + l)*TLEN + (TLEN-1)] = ((s01 + s23) + (s45 + s67)) + blin;
    }
}

extern "C" void kernel_launch(void* const* d_in, const int* in_sizes, int n_in,
                              void* d_out, int out_size, void* d_ws, size_t ws_size,
                              hipStream_t stream) {
    const float* x     = (const float*)d_in[0];
    const float* W_ih0 = (const float*)d_in[1];
    const float* W_hh0 = (const float*)d_in[2];
    const float* b_ih0 = (const float*)d_in[3];
    const float* b_hh0 = (const float*)d_in[4];
    const float* W_ih1 = (const float*)d_in[5];
    const float* W_hh1 = (const float*)d_in[6];
    const float* b_ih1 = (const float*)d_in[7];
    const float* b_hh1 = (const float*)d_in[8];
    const float* W_lin = (const float*)d_in[9];
    const float* b_lin = (const float*)d_in[10];
    float* out = (float*)d_out;

    const int B = in_sizes[0] / TLEN;
    lstm2_mfma<<<dim3(B / NBATCH), dim3(NTH), 0, stream>>>(
        x, W_ih0, W_hh0, b_ih0, b_hh0, W_ih1, W_hh1, b_ih1, b_hh1, W_lin, b_lin, out);
}

// Round 9
// 1473.059 us; speedup vs baseline: 1.0695x; 1.0695x over previous
//
#include <hip/hip_runtime.h>

#define HID 51
#define TLEN 1024
#define NBATCH 4
#define NW 16             // waves per block
#define NTH (NW * 64)

typedef __attribute__((ext_vector_type(8))) short bf16x8;
typedef __attribute__((ext_vector_type(4))) float f32x4;

#define LOG2E 1.4426950408889634f

__device__ __forceinline__ float frcp(float v){ return __builtin_amdgcn_rcpf(v); }
// input already scaled by log2e (or 2*log2e for tanh-gate)
__device__ __forceinline__ float sigm2(float v){ return frcp(1.f + __builtin_amdgcn_exp2f(-v)); }
__device__ __forceinline__ float tanh_c(float c){   // c in true domain
    return fmaf(2.f, frcp(1.f + __builtin_amdgcn_exp2f(-2.f*LOG2E*c)), -1.f);
}
__device__ __forceinline__ unsigned short f2bf(float f){
    unsigned u = __float_as_uint(f);
    return (unsigned short)((u + 0x7FFFu + ((u>>16)&1u)) >> 16);   // RNE f32->bf16
}
__device__ __forceinline__ float bf2f(unsigned short b){ return __uint_as_float(((unsigned)b)<<16); }

// LDS h layout = MFMA B-fragment-linear (validated R4): lane l reads 16B at
// short-index kb*512 + l*8 covering k = 32*kb + 8*(l>>4) + 0..7, n = l&15.
// Writer (unit j, col n): short-index = (j>>5)*512 + (n + ((j>>3)&3)*16)*8 + (j&7).

__global__ __launch_bounds__(NTH)   // single-arg: block size alone implies <=128 VGPR; no 64-cap
void lstm2_mfma(const float* __restrict__ x,
                const float* __restrict__ W_ih0, const float* __restrict__ W_hh0,
                const float* __restrict__ b_ih0, const float* __restrict__ b_hh0,
                const float* __restrict__ W_ih1, const float* __restrict__ W_hh1,
                const float* __restrict__ b_ih1, const float* __restrict__ b_hh1,
                const float* __restrict__ W_lin, const float* __restrict__ b_lin,
                float* __restrict__ out)
{
    const int tid = threadIdx.x;
    const int w = tid >> 6;          // wave 0..15; waves 0..12 compute tile m=w
    const int l = tid & 63;          // lane
    const int n = l & 15;            // batch col / A-row slot
    const int p = l >> 4;            // lane group 0..3
    const int m = w;                 // M-tile id
    const bool cw = (m < 13);        // compute wave?

    __shared__ short H0hi[2][1024], H0lo[2][1024];
    __shared__ short H1hi[2][1024], H1lo[2][1024];
    __shared__ __align__(16) float PS[2][16][16];

    for (int i = tid; i < 1024; i += NTH){
        H0hi[0][i]=0; H0hi[1][i]=0; H0lo[0][i]=0; H0lo[1][i]=0;
        H1hi[0][i]=0; H1hi[1][i]=0; H1lo[0][i]=0; H1lo[1][i]=0;
    }
    if (tid < 2*16*16) (&PS[0][0][0])[tid] = 0.f;

    // ---- persistent weight fragments & epilogue constants (one tile per wave) ----
    bf16x8 Ahi0[2], Alo0[2], Ahi1[4], Alo1[4];
    f32x4 bias0v, bias1v, wih0v;
    float wlinv = 0.f;
    int   widx4 = 0;

    {
        const int ar = 16*m + n;              // A-row = gate g = 4j + r
        const int aj = ar >> 2, arr = ar & 3;
        const bool rowv = cw && (aj < HID);
        const int orow = arr*HID + aj;
        const float gsc = (arr == 2) ? 2.f*LOG2E : LOG2E;   // pre-scale into exp2 domain
        #pragma unroll
        for (int kb=0; kb<2; ++kb){
            bf16x8 hi, lo;
            #pragma unroll
            for (int jj=0; jj<8; ++jj){
                const int k = kb*32 + 8*p + jj;
                const float wv = (rowv && k < HID) ? gsc * W_hh0[orow*HID + k] : 0.f;
                const unsigned short hb = f2bf(wv);
                hi[jj] = (short)hb;
                lo[jj] = (short)f2bf(wv - bf2f(hb));
            }
            Ahi0[kb] = hi; Alo0[kb] = lo;
        }
        #pragma unroll
        for (int kb=0; kb<4; ++kb){
            bf16x8 hi, lo;
            #pragma unroll
            for (int jj=0; jj<8; ++jj){
                const int k = kb*32 + 8*p + jj;   // 0..127: [h0 (64) ; h1 (64)]
                float wv = 0.f;
                if (rowv){
                    if (k < 64) { if (k < HID) wv = W_ih1[orow*HID + k]; }
                    else        { const int kk = k - 64; if (kk < HID) wv = W_hh1[orow*HID + kk]; }
                }
                wv *= gsc;
                const unsigned short hb = f2bf(wv);
                hi[jj] = (short)hb;
                lo[jj] = (short)f2bf(wv - bf2f(hb));
            }
            Ahi1[kb] = hi; Alo1[kb] = lo;
        }
        const int je = 4*m + p;               // unit this lane owns in epilogue
        const bool jev = cw && (je < HID);
        #pragma unroll
        for (int r4=0; r4<4; ++r4){
            const float gs4 = (r4 == 2) ? 2.f*LOG2E : LOG2E;
            const int oe = r4*HID + je;
            bias0v[r4] = jev ? gs4 * (b_ih0[oe] + b_hh0[oe]) : 0.f;
            bias1v[r4] = jev ? gs4 * (b_ih1[oe] + b_hh1[oe]) : 0.f;
            wih0v[r4] = jev ? gs4 * W_ih0[oe] : 0.f;
        }
        wlinv = jev ? W_lin[je] : 0.f;
        widx4 = ((je>>5)<<9) + (n + ((je>>3)&3)*16)*8 + (je&7);
    }

    const long long bb = (long long)blockIdx.x * NBATCH;
    const float* xr = x + (bb + (n < NBATCH ? n : NBATCH-1)) * TLEN;
    float xv = xr[0];
    float c0a = 0.f, c1a = 0.f;
    const float blin = b_lin[0];

    __syncthreads();

    // Pipelined loop: iter s = layer0(s) || layer1(s-1) || out(s-2). ONE barrier.
    for (int s = 0; s <= TLEN; ++s){
        const int pw = s & 1, pr = pw ^ 1;
        const float xnx = xr[(s+1 < TLEN) ? s+1 : TLEN-1];

        // h0(s-1) fragments (used by both layers)
        bf16x8 r0h[2], r0l[2];
        if (cw){
            #pragma unroll
            for (int kb=0; kb<2; ++kb){
                r0h[kb] = *reinterpret_cast<const bf16x8*>(&H0hi[pr][kb*512 + l*8]);
                r0l[kb] = *reinterpret_cast<const bf16x8*>(&H0lo[pr][kb*512 + l*8]);
            }
        }

        // out(s-2): wave 13 sums PS written at iter s-1 (cols w=13..15 stay 0)
        if (s >= 2 && w == 13 && l < NBATCH){
            const float4 p0 = *reinterpret_cast<const float4*>(&PS[pr][l][0]);
            const float4 p1 = *reinterpret_cast<const float4*>(&PS[pr][l][4]);
            const float4 p2 = *reinterpret_cast<const float4*>(&PS[pr][l][8]);
            const float4 p3 = *reinterpret_cast<const float4*>(&PS[pr][l][12]);
            const float s01 = (p0.x + p0.y) + (p0.z + p0.w);
            const float s23 = (p1.x + p1.y) + (p1.z + p1.w);
            const float s45 = (p2.x + p2.y) + (p2.z + p2.w);
            const float s67 = (p3.x + p3.y) + (p3.z + p3.w);
            out[(bb + l)*TLEN + (s-2)] = ((s01 + s23) + (s45 + s67)) + blin;
        }

        // ---------------- layer 0, step s ----------------
        if (cw && s < TLEN){
            f32x4 a0 = bias0v;
            #pragma unroll
            for (int r4=0; r4<4; ++r4) a0[r4] = fmaf(xv, wih0v[r4], a0[r4]);
            f32x4 a1 = {0.f,0.f,0.f,0.f};
            // two parallel chains, then one vector add
            a0 = __builtin_amdgcn_mfma_f32_16x16x32_bf16(Ahi0[0], r0h[0], a0, 0,0,0);
            a0 = __builtin_amdgcn_mfma_f32_16x16x32_bf16(Ahi0[1], r0h[1], a0, 0,0,0);
            a1 = __builtin_amdgcn_mfma_f32_16x16x32_bf16(Alo0[0], r0h[0], a1, 0,0,0);
            a1 = __builtin_amdgcn_mfma_f32_16x16x32_bf16(Alo0[1], r0h[1], a1, 0,0,0);
            a1 = __builtin_amdgcn_mfma_f32_16x16x32_bf16(Ahi0[0], r0l[0], a1, 0,0,0);
            a1 = __builtin_amdgcn_mfma_f32_16x16x32_bf16(Ahi0[1], r0l[1], a1, 0,0,0);
            const f32x4 pre = a0 + a1;
            const float gi = sigm2(pre[0]);
            const float gf = sigm2(pre[1]);
            const float gg = fmaf(2.f, sigm2(pre[2]), -1.f);   // tanh via 2*log2e prescale
            const float go = sigm2(pre[3]);
            c0a = fmaf(gf, c0a, gi*gg);
            const float hv = go * tanh_c(c0a);
            const unsigned short hh = f2bf(hv);
            H0hi[pw][widx4] = (short)hh;
            H0lo[pw][widx4] = (short)f2bf(hv - bf2f(hh));
        }

        // ---------------- layer 1, step s-1 + projection ----------------
        if (cw && s >= 1){
            // h1(s-2) fragments — loaded here to shorten live range
            bf16x8 r1h[2], r1l[2];
            #pragma unroll
            for (int kb=0; kb<2; ++kb){
                r1h[kb] = *reinterpret_cast<const bf16x8*>(&H1hi[pw][kb*512 + l*8]);
                r1l[kb] = *reinterpret_cast<const bf16x8*>(&H1lo[pw][kb*512 + l*8]);
            }
            f32x4 b0 = bias1v;
            f32x4 b1 = {0.f,0.f,0.f,0.f}, b2 = {0.f,0.f,0.f,0.f};
            // three parallel 4-deep chains
            b0 = __builtin_amdgcn_mfma_f32_16x16x32_bf16(Ahi1[0], r0h[0], b0, 0,0,0);
            b0 = __builtin_amdgcn_mfma_f32_16x16x32_bf16(Ahi1[1], r0h[1], b0, 0,0,0);
            b0 = __builtin_amdgcn_mfma_f32_16x16x32_bf16(Ahi1[2], r1h[0], b0, 0,0,0);
            b0 = __builtin_amdgcn_mfma_f32_16x16x32_bf16(Ahi1[3], r1h[1], b0, 0,0,0);
            b1 = __builtin_amdgcn_mfma_f32_16x16x32_bf16(Alo1[0], r0h[0], b1, 0,0,0);
            b1 = __builtin_amdgcn_mfma_f32_16x16x32_bf16(Alo1[1], r0h[1], b1, 0,0,0);
            b1 = __builtin_amdgcn_mfma_f32_16x16x32_bf16(Ahi1[0], r0l[0], b1, 0,0,0);
            b1 = __builtin_amdgcn_mfma_f32_16x16x32_bf16(Ahi1[1], r0l[1], b1, 0,0,0);
            b2 = __builtin_amdgcn_mfma_f32_16x16x32_bf16(Alo1[2], r1h[0], b2, 0,0,0);
            b2 = __builtin_amdgcn_mfma_f32_16x16x32_bf16(Alo1[3], r1h[1], b2, 0,0,0);
            b2 = __builtin_amdgcn_mfma_f32_16x16x32_bf16(Ahi1[2], r1l[0], b2, 0,0,0);
            b2 = __builtin_amdgcn_mfma_f32_16x16x32_bf16(Ahi1[3], r1l[1], b2, 0,0,0);
            const f32x4 pre = (b0 + b1) + b2;
            const float gi = sigm2(pre[0]);
            const float gf = sigm2(pre[1]);
            const float gg = fmaf(2.f, sigm2(pre[2]), -1.f);
            const float go = sigm2(pre[3]);
            c1a = fmaf(gf, c1a, gi*gg);
            const float hv = go * tanh_c(c1a);
            const unsigned short hh = f2bf(hv);
            H1hi[pr][widx4] = (short)hh;
            H1lo[pr][widx4] = (short)f2bf(hv - bf2f(hh));
            float ph = hv * wlinv;
            ph += __shfl_xor(ph, 16, 64);
            ph += __shfl_xor(ph, 32, 64);
            if (l < 16) PS[pw][l][w] = ph;
        }

        __syncthreads();
        xv = xnx;
    }

    // tail: out(1023) from PS written at s=1024 (parity 0)
    if (w == 13 && l < NBATCH){
        const float4 p0 = *reinterpret_cast<const float4*>(&PS[0][l][0]);
        const float4 p1 = *reinterpret_cast<const float4*>(&PS[0][l][4]);
        const float4 p2 = *reinterpret_cast<const float4*>(&PS[0][l][8]);
        const float4 p3 = *reinterpret_cast<const float4*>(&PS[0][l][12]);
        const float s01 = (p0.x + p0.y) + (p0.z + p0.w);
        const float s23 = (p1.x + p1.y) + (p1.z + p1.w);
        const float s45 = (p2.x + p2.y) + (p2.z + p2.w);
        const float s67 = (p3.x + p3.y) + (p3.z + p3.w);
        out[(bb + l)*TLEN + (TLEN-1)] = ((s01 + s23) + (s45 + s67)) + blin;
    }
}

extern "C" void kernel_launch(void* const* d_in, const int* in_sizes, int n_in,
                              void* d_out, int out_size, void* d_ws, size_t ws_size,
                              hipStream_t stream) {
    const float* x     = (const float*)d_in[0];
    const float* W_ih0 = (const float*)d_in[1];
    const float* W_hh0 = (const float*)d_in[2];
    const float* b_ih0 = (const float*)d_in[3];
    const float* b_hh0 = (const float*)d_in[4];
    const float* W_ih1 = (const float*)d_in[5];
    const float* W_hh1 = (const float*)d_in[6];
    const float* b_ih1 = (const float*)d_in[7];
    const float* b_hh1 = (const float*)d_in[8];
    const float* W_lin = (const float*)d_in[9];
    const float* b_lin = (const float*)d_in[10];
    float* out = (float*)d_out;

    const int B = in_sizes[0] / TLEN;
    lstm2_mfma<<<dim3(B / NBATCH), dim3(NTH), 0, stream>>>(
        x, W_ih0, W_hh0, b_ih0, b_hh0, W_ih1, W_hh1, b_ih1, b_hh1, W_lin, b_lin, out);
}

// Round 10
// 1293.256 us; speedup vs baseline: 1.2182x; 1.1390x over previous
//
#include <hip/hip_runtime.h>

#define HID 51
#define TLEN 1024
#define NBATCH 4
#define NW 16             // waves per block
#define NTH (NW * 64)

typedef __attribute__((ext_vector_type(8))) short bf16x8;
typedef __attribute__((ext_vector_type(4))) float f32x4;

#define LOG2E 1.4426950408889634f

__device__ __forceinline__ float frcp(float v){ return __builtin_amdgcn_rcpf(v); }
// input already scaled by log2e (or 2*log2e for tanh-gate)
__device__ __forceinline__ float sigm2(float v){ return frcp(1.f + __builtin_amdgcn_exp2f(-v)); }
__device__ __forceinline__ float tanh_c(float c){   // c in true domain
    return fmaf(2.f, frcp(1.f + __builtin_amdgcn_exp2f(-2.f*LOG2E*c)), -1.f);
}
__device__ __forceinline__ unsigned short f2bf(float f){
    unsigned u = __float_as_uint(f);
    return (unsigned short)((u + 0x7FFFu + ((u>>16)&1u)) >> 16);   // RNE f32->bf16
}
__device__ __forceinline__ float bf2f(unsigned short b){ return __uint_as_float(((unsigned)b)<<16); }
// single-value f32->bf16 via HW packed convert (low 16 bits of result)
__device__ __forceinline__ unsigned cvt1bf(float f){
    unsigned r; asm("v_cvt_pk_bf16_f32 %0, %1, 0" : "=v"(r) : "v"(f)); return r;
}

// LDS h layout = MFMA B-fragment-linear (validated R4): lane l reads 16B at
// short-index kb*512 + l*8 covering k = 32*kb + 8*(l>>4) + 0..7, n = l&15.
// Writer (unit j, col n): short-index = (j>>5)*512 + (n + ((j>>3)&3)*16)*8 + (j&7).

__global__ __launch_bounds__(NTH)   // block size alone implies <=128 VGPR cap
void lstm2_mfma(const float* __restrict__ x,
                const float* __restrict__ W_ih0, const float* __restrict__ W_hh0,
                const float* __restrict__ b_ih0, const float* __restrict__ b_hh0,
                const float* __restrict__ W_ih1, const float* __restrict__ W_hh1,
                const float* __restrict__ b_ih1, const float* __restrict__ b_hh1,
                const float* __restrict__ W_lin, const float* __restrict__ b_lin,
                float* __restrict__ out)
{
    const int tid = threadIdx.x;
    const int w = tid >> 6;          // wave 0..15; waves 0..12 compute tile m=w
    const int l = tid & 63;          // lane
    const int n = l & 15;            // batch col / A-row slot
    const int p = l >> 4;            // lane group 0..3
    const int m = w;                 // M-tile id
    const bool cw = (m < 13);        // compute wave?

    __shared__ short H0hi[2][1024], H0lo[2][1024];
    __shared__ short H1hi[2][1024], H1lo[2][1024];
    __shared__ __align__(16) float PS[2][16][20];   // [parity][col][wave(+pad)]

    for (int i = tid; i < 1024; i += NTH){
        H0hi[0][i]=0; H0hi[1][i]=0; H0lo[0][i]=0; H0lo[1][i]=0;
        H1hi[0][i]=0; H1hi[1][i]=0; H1lo[0][i]=0; H1lo[1][i]=0;
    }
    if (tid < 2*16*20) (&PS[0][0][0])[tid] = 0.f;

    // ---- persistent weight fragments & epilogue constants (one tile per wave) ----
    bf16x8 Ahi0[2], Alo0[2], Ahi1[4], Alo1[4];
    f32x4 bias0v, bias1v, wih0v;
    float wlinv = 0.f;
    int   widx4 = 0;

    {
        const int ar = 16*m + n;              // A-row = gate g = 4j + r
        const int aj = ar >> 2, arr = ar & 3;
        const bool rowv = cw && (aj < HID);
        const int orow = arr*HID + aj;
        const float gsc = (arr == 2) ? 2.f*LOG2E : LOG2E;   // pre-scale into exp2 domain
        #pragma unroll
        for (int kb=0; kb<2; ++kb){
            bf16x8 hi, lo;
            #pragma unroll
            for (int jj=0; jj<8; ++jj){
                const int k = kb*32 + 8*p + jj;
                const float wv = (rowv && k < HID) ? gsc * W_hh0[orow*HID + k] : 0.f;
                const unsigned short hb = f2bf(wv);
                hi[jj] = (short)hb;
                lo[jj] = (short)f2bf(wv - bf2f(hb));
            }
            Ahi0[kb] = hi; Alo0[kb] = lo;
        }
        #pragma unroll
        for (int kb=0; kb<4; ++kb){
            bf16x8 hi, lo;
            #pragma unroll
            for (int jj=0; jj<8; ++jj){
                const int k = kb*32 + 8*p + jj;   // 0..127: [h0 (64) ; h1 (64)]
                float wv = 0.f;
                if (rowv){
                    if (k < 64) { if (k < HID) wv = W_ih1[orow*HID + k]; }
                    else        { const int kk = k - 64; if (kk < HID) wv = W_hh1[orow*HID + kk]; }
                }
                wv *= gsc;
                const unsigned short hb = f2bf(wv);
                hi[jj] = (short)hb;
                lo[jj] = (short)f2bf(wv - bf2f(hb));
            }
            Ahi1[kb] = hi; Alo1[kb] = lo;
        }
        const int je = 4*m + p;               // unit this lane owns in epilogue
        const bool jev = cw && (je < HID);
        #pragma unroll
        for (int r4=0; r4<4; ++r4){
            const float gs4 = (r4 == 2) ? 2.f*LOG2E : LOG2E;
            const int oe = r4*HID + je;
            bias0v[r4] = jev ? gs4 * (b_ih0[oe] + b_hh0[oe]) : 0.f;
            bias1v[r4] = jev ? gs4 * (b_ih1[oe] + b_hh1[oe]) : 0.f;
            wih0v[r4] = jev ? gs4 * W_ih0[oe] : 0.f;
        }
        wlinv = jev ? W_lin[je] : 0.f;
        widx4 = ((je>>5)<<9) + (n + ((je>>3)&3)*16)*8 + (je&7);
    }

    const long long bb = (long long)blockIdx.x * NBATCH;
    const float* xr = x + (bb + (n < NBATCH ? n : NBATCH-1)) * TLEN;
    float xv = xr[0];
    float c0a = 0.f, c1a = 0.f;
    const float blin = b_lin[0];

    __syncthreads();

    // Pipelined loop: iter s = layer0(s) || layer1(s-1) || out(s-2). ONE barrier.
    // Stagger: even waves L0 then L1; odd waves L1 then L0 (phases independent).
    for (int s = 0; s <= TLEN; ++s){
        const int pw = s & 1, pr = pw ^ 1;
        const float xnx = xr[(s+1 < TLEN) ? s+1 : TLEN-1];

        // h0(s-1) fragments (used by both layers)
        bf16x8 r0h[2], r0l[2];
        if (cw){
            #pragma unroll
            for (int kb=0; kb<2; ++kb){
                r0h[kb] = *reinterpret_cast<const bf16x8*>(&H0hi[pr][kb*512 + l*8]);
                r0l[kb] = *reinterpret_cast<const bf16x8*>(&H0lo[pr][kb*512 + l*8]);
            }
        }

        // out(s-2): wave 13 sums PS written at iter s-1 (w>=13 columns stay 0)
        if (s >= 2 && w == 13 && l < NBATCH){
            const float4 p0 = *reinterpret_cast<const float4*>(&PS[pr][l][0]);
            const float4 p1 = *reinterpret_cast<const float4*>(&PS[pr][l][4]);
            const float4 p2 = *reinterpret_cast<const float4*>(&PS[pr][l][8]);
            const float4 p3 = *reinterpret_cast<const float4*>(&PS[pr][l][12]);
            const float s01 = (p0.x + p0.y) + (p0.z + p0.w);
            const float s23 = (p1.x + p1.y) + (p1.z + p1.w);
            const float s45 = (p2.x + p2.y) + (p2.z + p2.w);
            const float s67 = (p3.x + p3.y) + (p3.z + p3.w);
            out[(bb + l)*TLEN + (s-2)] = ((s01 + s23) + (s45 + s67)) + blin;
        }

        // ---------------- layer 0, step s ----------------
        auto doL0 = [&](){
            if (cw && s < TLEN){
                f32x4 a0 = bias0v;
                #pragma unroll
                for (int r4=0; r4<4; ++r4) a0[r4] = fmaf(xv, wih0v[r4], a0[r4]);
                f32x4 a1 = {0.f,0.f,0.f,0.f};
                __builtin_amdgcn_s_setprio(1);
                a0 = __builtin_amdgcn_mfma_f32_16x16x32_bf16(Ahi0[0], r0h[0], a0, 0,0,0);
                a0 = __builtin_amdgcn_mfma_f32_16x16x32_bf16(Ahi0[1], r0h[1], a0, 0,0,0);
                a1 = __builtin_amdgcn_mfma_f32_16x16x32_bf16(Alo0[0], r0h[0], a1, 0,0,0);
                a1 = __builtin_amdgcn_mfma_f32_16x16x32_bf16(Alo0[1], r0h[1], a1, 0,0,0);
                a1 = __builtin_amdgcn_mfma_f32_16x16x32_bf16(Ahi0[0], r0l[0], a1, 0,0,0);
                a1 = __builtin_amdgcn_mfma_f32_16x16x32_bf16(Ahi0[1], r0l[1], a1, 0,0,0);
                __builtin_amdgcn_s_setprio(0);
                const f32x4 pre = a0 + a1;
                const float gi = sigm2(pre[0]);
                const float gf = sigm2(pre[1]);
                const float gg = fmaf(2.f, sigm2(pre[2]), -1.f);
                const float go = sigm2(pre[3]);
                c0a = fmaf(gf, c0a, gi*gg);
                const float hv = go * tanh_c(c0a);
                const unsigned u0 = cvt1bf(hv);
                const unsigned u1 = cvt1bf(hv - __uint_as_float(u0 << 16));
                H0hi[pw][widx4] = (short)u0;
                H0lo[pw][widx4] = (short)u1;
            }
        };

        // ---------------- layer 1, step s-1 + projection ----------------
        auto doL1 = [&](){
            if (cw && s >= 1){
                bf16x8 r1h[2], r1l[2];
                #pragma unroll
                for (int kb=0; kb<2; ++kb){
                    r1h[kb] = *reinterpret_cast<const bf16x8*>(&H1hi[pw][kb*512 + l*8]);
                    r1l[kb] = *reinterpret_cast<const bf16x8*>(&H1lo[pw][kb*512 + l*8]);
                }
                f32x4 b0 = bias1v;
                f32x4 b1 = {0.f,0.f,0.f,0.f}, b2 = {0.f,0.f,0.f,0.f};
                __builtin_amdgcn_s_setprio(1);
                b0 = __builtin_amdgcn_mfma_f32_16x16x32_bf16(Ahi1[0], r0h[0], b0, 0,0,0);
                b0 = __builtin_amdgcn_mfma_f32_16x16x32_bf16(Ahi1[1], r0h[1], b0, 0,0,0);
                b0 = __builtin_amdgcn_mfma_f32_16x16x32_bf16(Ahi1[2], r1h[0], b0, 0,0,0);
                b0 = __builtin_amdgcn_mfma_f32_16x16x32_bf16(Ahi1[3], r1h[1], b0, 0,0,0);
                b1 = __builtin_amdgcn_mfma_f32_16x16x32_bf16(Alo1[0], r0h[0], b1, 0,0,0);
                b1 = __builtin_amdgcn_mfma_f32_16x16x32_bf16(Alo1[1], r0h[1], b1, 0,0,0);
                b1 = __builtin_amdgcn_mfma_f32_16x16x32_bf16(Ahi1[0], r0l[0], b1, 0,0,0);
                b1 = __builtin_amdgcn_mfma_f32_16x16x32_bf16(Ahi1[1], r0l[1], b1, 0,0,0);
                b2 = __builtin_amdgcn_mfma_f32_16x16x32_bf16(Alo1[2], r1h[0], b2, 0,0,0);
                b2 = __builtin_amdgcn_mfma_f32_16x16x32_bf16(Alo1[3], r1h[1], b2, 0,0,0);
                b2 = __builtin_amdgcn_mfma_f32_16x16x32_bf16(Ahi1[2], r1l[0], b2, 0,0,0);
                b2 = __builtin_amdgcn_mfma_f32_16x16x32_bf16(Ahi1[3], r1l[1], b2, 0,0,0);
                __builtin_amdgcn_s_setprio(0);
                const f32x4 pre = (b0 + b1) + b2;
                const float gi = sigm2(pre[0]);
                const float gf = sigm2(pre[1]);
                const float gg = fmaf(2.f, sigm2(pre[2]), -1.f);
                const float go = sigm2(pre[3]);
                c1a = fmaf(gf, c1a, gi*gg);
                const float hv = go * tanh_c(c1a);
                const unsigned u0 = cvt1bf(hv);
                const unsigned u1 = cvt1bf(hv - __uint_as_float(u0 << 16));
                H1hi[pr][widx4] = (short)u0;
                H1lo[pr][widx4] = (short)u1;
                float ph = hv * wlinv;
                ph += __shfl_xor(ph, 16, 64);
                ph += __shfl_xor(ph, 32, 64);
                if (l < 16) PS[pw][l][w] = ph;
            }
        };

        if (w & 1){ doL1(); doL0(); } else { doL0(); doL1(); }

        __syncthreads();
        xv = xnx;
    }

    // tail: out(1023) from PS written at s=1024 (parity 0)
    if (w == 13 && l < NBATCH){
        const float4 p0 = *reinterpret_cast<const float4*>(&PS[0][l][0]);
        const float4 p1 = *reinterpret_cast<const float4*>(&PS[0][l][4]);
        const float4 p2 = *reinterpret_cast<const float4*>(&PS[0][l][8]);
        const float4 p3 = *reinterpret_cast<const float4*>(&PS[0][l][12]);
        const float s01 = (p0.x + p0.y) + (p0.z + p0.w);
        const float s23 = (p1.x + p1.y) + (p1.z + p1.w);
        const float s45 = (p2.x + p2.y) + (p2.z + p2.w);
        const float s67 = (p3.x + p3.y) + (p3.z + p3.w);
        out[(bb + l)*TLEN + (TLEN-1)] = ((s01 + s23) + (s45 + s67)) + blin;
    }
}

extern "C" void kernel_launch(void* const* d_in, const int* in_sizes, int n_in,
                              void* d_out, int out_size, void* d_ws, size_t ws_size,
                              hipStream_t stream) {
    const float* x     = (const float*)d_in[0];
    const float* W_ih0 = (const float*)d_in[1];
    const float* W_hh0 = (const float*)d_in[2];
    const float* b_ih0 = (const float*)d_in[3];
    const float* b_hh0 = (const float*)d_in[4];
    const float* W_ih1 = (const float*)d_in[5];
    const float* W_hh1 = (const float*)d_in[6];
    const float* b_ih1 = (const float*)d_in[7];
    const float* b_hh1 = (const float*)d_in[8];
    const float* W_lin = (const float*)d_in[9];
    const float* b_lin = (const float*)d_in[10];
    float* out = (float*)d_out;

    const int B = in_sizes[0] / TLEN;
    lstm2_mfma<<<dim3(B / NBATCH), dim3(NTH), 0, stream>>>(
        x, W_ih0, W_hh0, b_ih0, b_hh0, W_ih1, W_hh1, b_ih1, b_hh1, W_lin, b_lin, out);
}